// Round 1
// baseline (545.835 us; speedup 1.0000x reference)
//
#include <hip/hip_runtime.h>
#include <stdint.h>

typedef int   i32x4 __attribute__((ext_vector_type(4)));
typedef float f32x4 __attribute__((ext_vector_type(4)));

#define AS1 __attribute__((address_space(1)))
#define AS3 __attribute__((address_space(3)))
#define G2L16(gp, lp) __builtin_amdgcn_global_load_lds((const AS1 void*)(gp), (AS3 void*)(lp), 16, 0, 0)

// ---------------- symmetric int8 row quantization ----------------
// One 256-thread block per row. COLS must be 4096 (PER=16 -> one 16B store/thread).
template<int COLS>
__global__ __launch_bounds__(256)
void quant_rows_k(const float* __restrict__ src, int8_t* __restrict__ q,
                  float* __restrict__ scale)
{
    constexpr int PER = COLS / 256;   // 16
    static_assert(PER == 16, "pack assumes 16 elems/thread");
    const int row = blockIdx.x;
    const int t   = threadIdx.x;
    const float* s = src + (size_t)row * COLS + (size_t)t * PER;

    float v[PER];
    #pragma unroll
    for (int i = 0; i < PER; i += 4) {
        f32x4 x4 = *reinterpret_cast<const f32x4*>(s + i);
        v[i+0] = x4[0]; v[i+1] = x4[1]; v[i+2] = x4[2]; v[i+3] = x4[3];
    }
    float amax = 0.0f;
    #pragma unroll
    for (int i = 0; i < PER; ++i) amax = fmaxf(amax, fabsf(v[i]));

    #pragma unroll
    for (int off = 32; off > 0; off >>= 1)
        amax = fmaxf(amax, __shfl_xor(amax, off, 64));

    __shared__ float red[4];
    if ((t & 63) == 0) red[t >> 6] = amax;
    __syncthreads();
    amax = fmaxf(fmaxf(red[0], red[1]), fmaxf(red[2], red[3]));

    const float sc = fmaxf(amax, 1e-8f) / 127.0f;   // matches reference exactly
    if (t == 0) scale[row] = sc;

    union { i32x4 v4; int8_t b[16]; } pk;
    #pragma unroll
    for (int i = 0; i < PER; ++i) {
        float r = rintf(v[i] / sc);                 // round-half-even like jnp.round
        r = fminf(127.0f, fmaxf(-127.0f, r));
        pk.b[i] = (int8_t)r;
    }
    *reinterpret_cast<i32x4*>(q + (size_t)row * COLS + (size_t)t * PER) = pk.v4;
}

// ---------------- int8 GEMM: C[M][N] = A[M][K] * B[N][K]^T, fused dequant ----------------
// 128x128 tile, BK=64, 256 threads = 4 waves, each wave owns a 64x64 sub-tile
// (4x4 fragments of mfma_i32_16x16x64_i8). Double-buffered LDS staged with
// global_load_lds width=16 (linear dest = base + tid*16).
#define BM 128
#define BN 128
#define BK 64

__global__ __launch_bounds__(256)
void gemm_i8_k(const int8_t* __restrict__ A,    // [M][K]
               const int8_t* __restrict__ B,    // [N][K]  (= quantized weight rows)
               const float*  __restrict__ sx,   // [M]
               const float*  __restrict__ sw,   // [N]
               const float*  __restrict__ bias, // [N]
               float* __restrict__ C,           // [M][N]
               int M, int N, int K)
{
    __shared__ int8_t lA[2][BM * BK];   // 2 x 8 KiB
    __shared__ int8_t lB[2][BN * BK];   // 2 x 8 KiB

    const int t    = threadIdx.x;
    const int lane = t & 63;
    const int wid  = t >> 6;
    const int wm   = wid >> 1;   // wave row 0..1
    const int wn   = wid & 1;    // wave col 0..1

    // XCD-aware swizzle (grid is a multiple of 8 for this shape)
    const int nwg = (int)gridDim.x;
    const int bid = (int)blockIdx.x;
    const int swz = ((nwg & 7) == 0) ? ((bid & 7) * (nwg >> 3) + (bid >> 3)) : bid;
    const int nbn = N / BN;
    const int bm  = swz / nbn;
    const int bn  = swz % nbn;

    // staging: thread t covers tile row (t>>2), 16B chunk (t&3); two 64-row halves
    const int srow = t >> 2;
    const int soff = (t & 3) * 16;
    const int8_t* gA = A + (size_t)(bm * BM + srow) * K + soff;
    const int8_t* gB = B + (size_t)(bn * BN + srow) * K + soff;
    const size_t half = (size_t)64 * K;

    i32x4 acc[4][4] = {};

    const int NK = K / BK;
    const int frow = lane & 15;          // fragment row (A) / out-channel (B)
    const int fk   = (lane >> 4) * 16;   // k-chunk byte offset within BK

    // prologue: stage tile 0 into buffer 0
    {
        int8_t* la = &lA[0][0];
        int8_t* lb = &lB[0][0];
        G2L16(gA,        la + t * 16);
        G2L16(gA + half, la + 4096 + t * 16);
        G2L16(gB,        lb + t * 16);
        G2L16(gB + half, lb + 4096 + t * 16);
    }
    __syncthreads();   // drains vmcnt(0): tile 0 resident

    int cur = 0;
    for (int kt = 0; kt < NK; ++kt) {
        if (kt + 1 < NK) {   // prefetch next tile into other buffer
            const int8_t* pa = gA + (kt + 1) * BK;
            const int8_t* pb = gB + (kt + 1) * BK;
            int8_t* la = &lA[cur ^ 1][0];
            int8_t* lb = &lB[cur ^ 1][0];
            G2L16(pa,        la + t * 16);
            G2L16(pa + half, la + 4096 + t * 16);
            G2L16(pb,        lb + t * 16);
            G2L16(pb + half, lb + 4096 + t * 16);
        }
        const int8_t* pa = &lA[cur][(wm * 64 + frow) * BK + fk];
        const int8_t* pb = &lB[cur][(wn * 64 + frow) * BK + fk];
        i32x4 af[4], bf[4];
        #pragma unroll
        for (int i = 0; i < 4; ++i)
            af[i] = *reinterpret_cast<const i32x4*>(pa + i * 16 * BK);
        #pragma unroll
        for (int i = 0; i < 4; ++i)
            bf[i] = *reinterpret_cast<const i32x4*>(pb + i * 16 * BK);
        #pragma unroll
        for (int mi = 0; mi < 4; ++mi)
            #pragma unroll
            for (int ni = 0; ni < 4; ++ni)
                acc[mi][ni] = __builtin_amdgcn_mfma_i32_16x16x64_i8(af[mi], bf[ni], acc[mi][ni], 0, 0, 0);
        __syncthreads();   // drains vmcnt (prefetch done) + lgkmcnt (reads done)
        cur ^= 1;
    }

    // epilogue: dequant + bias, fused
    const int r0 = bm * BM + wm * 64 + ((lane >> 4) << 2);
    const int c0 = bn * BN + wn * 64 + (lane & 15);
    #pragma unroll
    for (int ni = 0; ni < 4; ++ni) {
        const int c = c0 + ni * 16;
        const float swc = sw[c];
        const float bc  = bias[c];
        #pragma unroll
        for (int mi = 0; mi < 4; ++mi) {
            const int rbase = r0 + mi * 16;
            #pragma unroll
            for (int j = 0; j < 4; ++j) {
                const int r = rbase + j;
                C[(size_t)r * N + c] = (float)acc[mi][ni][j] * sx[r] * swc + bc;
            }
        }
    }
}

extern "C" void kernel_launch(void* const* d_in, const int* in_sizes, int n_in,
                              void* d_out, int out_size, void* d_ws, size_t ws_size,
                              hipStream_t stream) {
    const float* x    = (const float*)d_in[0];
    const float* w    = (const float*)d_in[1];
    const float* bias = (const float*)d_in[2];
    float* out = (float*)d_out;

    const int dout   = in_sizes[2];          // 16384
    const int din    = in_sizes[1] / dout;   // 4096
    const int tokens = in_sizes[0] / din;    // 4096

    // workspace layout: sx | sw | xq | wq  (~82 MB)
    char* ws = (char*)d_ws;
    float*  sx = (float*)ws;                                   // tokens f32
    float*  sw = (float*)(ws + 16384);                         // dout f32
    int8_t* xq = (int8_t*)(ws + 16384 + 65536);                // tokens*din
    int8_t* wq = xq + (size_t)tokens * din;                    // dout*din

    quant_rows_k<4096><<<tokens, 256, 0, stream>>>(x, xq, sx);
    quant_rows_k<4096><<<dout,   256, 0, stream>>>(w, wq, sw);

    const int grid = (tokens / BM) * (dout / BN);
    gemm_i8_k<<<grid, 256, 0, stream>>>(xq, wq, sx, sw, bias, out, tokens, dout, din);
}

// Round 2
// 443.949 us; speedup vs baseline: 1.2295x; 1.2295x over previous
//
#include <hip/hip_runtime.h>
#include <stdint.h>

typedef int   i32x4 __attribute__((ext_vector_type(4)));
typedef float f32x4 __attribute__((ext_vector_type(4)));

#define AS1 __attribute__((address_space(1)))
#define AS3 __attribute__((address_space(3)))
#define G2L16(gp, lp) __builtin_amdgcn_global_load_lds((const AS1 void*)(gp), (AS3 void*)(lp), 16, 0, 0)

// ---------------- symmetric int8 row quantization (unchanged, at BW floor) ----------------
template<int COLS>
__global__ __launch_bounds__(256)
void quant_rows_k(const float* __restrict__ src, int8_t* __restrict__ q,
                  float* __restrict__ scale)
{
    constexpr int PER = COLS / 256;   // 16
    static_assert(PER == 16, "pack assumes 16 elems/thread");
    const int row = blockIdx.x;
    const int t   = threadIdx.x;
    const float* s = src + (size_t)row * COLS + (size_t)t * PER;

    float v[PER];
    #pragma unroll
    for (int i = 0; i < PER; i += 4) {
        f32x4 x4 = *reinterpret_cast<const f32x4*>(s + i);
        v[i+0] = x4[0]; v[i+1] = x4[1]; v[i+2] = x4[2]; v[i+3] = x4[3];
    }
    float amax = 0.0f;
    #pragma unroll
    for (int i = 0; i < PER; ++i) amax = fmaxf(amax, fabsf(v[i]));

    #pragma unroll
    for (int off = 32; off > 0; off >>= 1)
        amax = fmaxf(amax, __shfl_xor(amax, off, 64));

    __shared__ float red[4];
    if ((t & 63) == 0) red[t >> 6] = amax;
    __syncthreads();
    amax = fmaxf(fmaxf(red[0], red[1]), fmaxf(red[2], red[3]));

    const float sc = fmaxf(amax, 1e-8f) / 127.0f;
    if (t == 0) scale[row] = sc;

    union { i32x4 v4; int8_t b[16]; } pk;
    #pragma unroll
    for (int i = 0; i < PER; ++i) {
        float r = rintf(v[i] / sc);
        r = fminf(127.0f, fmaxf(-127.0f, r));
        pk.b[i] = (int8_t)r;
    }
    *reinterpret_cast<i32x4*>(q + (size_t)row * COLS + (size_t)t * PER) = pk.v4;
}

// ---------------- int8 GEMM, 256x256 tile, 8-phase-style schedule ----------------
// 512 threads = 8 waves (2M x 4N), wave tile 128x64, BK = 128 bytes (2 MFMA k-slices).
// LDS: 2 dbuf x (A 256x128B + B 256x128B) = 128 KiB. Stage via global_load_lds w=16,
// linear LDS dest + pre-swizzled global source; ds_read uses the same XOR swizzle
// (chunk ^= row&7) -> every 8-lane phase hits 8 distinct bank groups.
#define BM 256
#define BN 256
#define BKB 128

__device__ __forceinline__ i32x4 mfma_i8(i32x4 a, i32x4 b, i32x4 c) {
    return __builtin_amdgcn_mfma_i32_16x16x64_i8(a, b, c, 0, 0, 0);
}

template<int P>
__device__ __forceinline__ void phase_fn(
    const int8_t* __restrict__ aB, const int8_t* __restrict__ bB,
    int kc0, int kc1,
    i32x4 (&acc)[8][4], i32x4 (&bf)[4][2],
    const int8_t* __restrict__ gSt, int8_t* lSt, size_t row64, int t16, bool doStage)
{
    // ds-load this phase's A fragments (mi = 2P, 2P+1) x 2 k-slices
    i32x4 a00 = *reinterpret_cast<const i32x4*>(aB + (2*P)   * 2048 + kc0);
    i32x4 a01 = *reinterpret_cast<const i32x4*>(aB + (2*P)   * 2048 + kc1);
    i32x4 a10 = *reinterpret_cast<const i32x4*>(aB + (2*P+1) * 2048 + kc0);
    i32x4 a11 = *reinterpret_cast<const i32x4*>(aB + (2*P+1) * 2048 + kc1);
    if (P == 0) {   // B fragments for the whole K-tile, once
        #pragma unroll
        for (int ni = 0; ni < 4; ++ni) {
            bf[ni][0] = *reinterpret_cast<const i32x4*>(bB + ni * 2048 + kc0);
            bf[ni][1] = *reinterpret_cast<const i32x4*>(bB + ni * 2048 + kc1);
        }
    }
    if (doStage) {  // stage one half-tile of a future K-tile into the OTHER buffer
        G2L16(gSt,         lSt + t16);
        G2L16(gSt + row64, lSt + 8192 + t16);
    }
    asm volatile("" ::: "memory");
    __builtin_amdgcn_s_barrier();
    asm volatile("s_waitcnt lgkmcnt(0)" ::: "memory");
    __builtin_amdgcn_sched_barrier(0);
    __builtin_amdgcn_s_setprio(1);
    #pragma unroll
    for (int ni = 0; ni < 4; ++ni) {
        acc[2*P  ][ni] = mfma_i8(a00, bf[ni][0], acc[2*P  ][ni]);
        acc[2*P  ][ni] = mfma_i8(a01, bf[ni][1], acc[2*P  ][ni]);
        acc[2*P+1][ni] = mfma_i8(a10, bf[ni][0], acc[2*P+1][ni]);
        acc[2*P+1][ni] = mfma_i8(a11, bf[ni][1], acc[2*P+1][ni]);
    }
    __builtin_amdgcn_s_setprio(0);
    asm volatile("" ::: "memory");
    __builtin_amdgcn_s_barrier();
}

__global__ __launch_bounds__(512, 2)
void gemm_i8_k(const int8_t* __restrict__ A,    // [M][K]
               const int8_t* __restrict__ B,    // [N][K]
               const float*  __restrict__ sx,   // [M]
               const float*  __restrict__ sw,   // [N]
               const float*  __restrict__ bias, // [N]
               float* __restrict__ C,           // [M][N]
               int M, int N, int K)
{
    __shared__ int8_t lA[2][BM * BKB];   // 2 x 32 KiB
    __shared__ int8_t lB[2][BN * BKB];   // 2 x 32 KiB

    const int t    = threadIdx.x;
    const int lane = t & 63;
    const int wid  = t >> 6;
    const int wm   = wid >> 2;   // 0..1
    const int wn   = wid & 3;    // 0..3

    const int nwg = (int)gridDim.x;
    const int bid = (int)blockIdx.x;
    const int swz = ((nwg & 7) == 0) ? ((bid & 7) * (nwg >> 3) + (bid >> 3)) : bid;
    const int nbn = N / BN;
    const int bm  = swz / nbn;
    const int bn  = swz % nbn;

    // fragment-read addressing (swizzled)
    const int fr  = lane & 15;
    const int c4  = lane >> 4;
    const int sw8 = fr & 7;
    const int kc0 = ((c4    ) ^ sw8) * 16;
    const int kc1 = ((c4 + 4) ^ sw8) * 16;
    const int8_t* aB0 = &lA[0][(wm * 128 + fr) * BKB];
    const int8_t* aB1 = &lA[1][(wm * 128 + fr) * BKB];
    const int8_t* bB0 = &lB[0][(wn * 64  + fr) * BKB];
    const int8_t* bB1 = &lB[1][(wn * 64  + fr) * BKB];

    // staging addressing: thread t covers chunks t and t+512 of a 128-row half
    // (linear LDS dest; global source pre-swizzled: chunk ^= row&7)
    const int srow = t >> 3;                          // 0..63
    const int skc  = ((t & 7) ^ (srow & 7)) * 16;
    const int t16  = t * 16;
    const int8_t* pA = A + (size_t)(bm * BM + srow) * K + skc;
    const int8_t* pB = B + (size_t)(bn * BN + srow) * K + skc;
    const size_t row64  = (size_t)64  * K;
    const size_t row128 = (size_t)128 * K;

    // prologue: stage K-tile 0 into buffer 0 (A: 2 halves, B: 2 halves)
    G2L16(pA,                  &lA[0][0]     + t16);
    G2L16(pA + row64,          &lA[0][8192]  + t16);
    G2L16(pA + row128,         &lA[0][16384] + t16);
    G2L16(pA + row128 + row64, &lA[0][24576] + t16);
    G2L16(pB,                  &lB[0][0]     + t16);
    G2L16(pB + row64,          &lB[0][8192]  + t16);
    G2L16(pB + row128,         &lB[0][16384] + t16);
    G2L16(pB + row128 + row64, &lB[0][24576] + t16);

    i32x4 acc[8][4] = {};
    i32x4 bf[4][2];

    const int NT = K / BKB;   // 32
    for (int tt = 0; tt < NT; tt += 2) {
        // ---- K-tile tt: read buf0, stage tile tt+1 -> buf1 ----
        {
            asm volatile("s_waitcnt vmcnt(0)" ::: "memory");
            __builtin_amdgcn_s_barrier();
            asm volatile("" ::: "memory");
            const size_t ko = (size_t)(tt + 1) * BKB;
            phase_fn<0>(aB0, bB0, kc0, kc1, acc, bf, pA + ko,          &lA[1][0],     row64, t16, true);
            phase_fn<1>(aB0, bB0, kc0, kc1, acc, bf, pA + row128 + ko, &lA[1][16384], row64, t16, true);
            phase_fn<2>(aB0, bB0, kc0, kc1, acc, bf, pB + ko,          &lB[1][0],     row64, t16, true);
            phase_fn<3>(aB0, bB0, kc0, kc1, acc, bf, pB + row128 + ko, &lB[1][16384], row64, t16, true);
        }
        // ---- K-tile tt+1: read buf1, stage tile tt+2 -> buf0 ----
        {
            asm volatile("s_waitcnt vmcnt(0)" ::: "memory");
            __builtin_amdgcn_s_barrier();
            asm volatile("" ::: "memory");
            const bool st = (tt + 2) < NT;
            const size_t ko = st ? (size_t)(tt + 2) * BKB : 0;
            phase_fn<0>(aB1, bB1, kc0, kc1, acc, bf, pA + ko,          &lA[0][0],     row64, t16, st);
            phase_fn<1>(aB1, bB1, kc0, kc1, acc, bf, pA + row128 + ko, &lA[0][16384], row64, t16, st);
            phase_fn<2>(aB1, bB1, kc0, kc1, acc, bf, pB + ko,          &lB[0][0],     row64, t16, st);
            phase_fn<3>(aB1, bB1, kc0, kc1, acc, bf, pB + row128 + ko, &lB[0][16384], row64, t16, st);
        }
    }

    // epilogue: dequant + bias
    const int r0 = bm * BM + wm * 128 + (c4 << 2);
    const int c0 = bn * BN + wn * 64 + fr;
    #pragma unroll
    for (int ni = 0; ni < 4; ++ni) {
        const int c = c0 + ni * 16;
        const float swc = sw[c];
        const float bc  = bias[c];
        #pragma unroll
        for (int mi = 0; mi < 8; ++mi) {
            const int rb = r0 + mi * 16;
            #pragma unroll
            for (int j = 0; j < 4; ++j) {
                const int r = rb + j;
                C[(size_t)r * N + c] = (float)acc[mi][ni][j] * sx[r] * swc + bc;
            }
        }
    }
}

extern "C" void kernel_launch(void* const* d_in, const int* in_sizes, int n_in,
                              void* d_out, int out_size, void* d_ws, size_t ws_size,
                              hipStream_t stream) {
    const float* x    = (const float*)d_in[0];
    const float* w    = (const float*)d_in[1];
    const float* bias = (const float*)d_in[2];
    float* out = (float*)d_out;

    const int dout   = in_sizes[2];          // 16384
    const int din    = in_sizes[1] / dout;   // 4096
    const int tokens = in_sizes[0] / din;    // 4096

    char* ws = (char*)d_ws;
    float*  sx = (float*)ws;
    float*  sw = (float*)(ws + 16384);
    int8_t* xq = (int8_t*)(ws + 16384 + 65536);
    int8_t* wq = xq + (size_t)tokens * din;

    quant_rows_k<4096><<<tokens, 256, 0, stream>>>(x, xq, sx);
    quant_rows_k<4096><<<dout,   256, 0, stream>>>(w, wq, sw);

    const int grid = (tokens / BM) * (dout / BN);
    gemm_i8_k<<<grid, 512, 0, stream>>>(xq, wq, sx, sw, bias, out, tokens, dout, din);
}

// Round 3
// 422.784 us; speedup vs baseline: 1.2910x; 1.0501x over previous
//
#include <hip/hip_runtime.h>
#include <stdint.h>

typedef int   i32x4 __attribute__((ext_vector_type(4)));
typedef float f32x4 __attribute__((ext_vector_type(4)));

#define AS1 __attribute__((address_space(1)))
#define AS3 __attribute__((address_space(3)))
#define G2L16(gp, lp) __builtin_amdgcn_global_load_lds((const AS1 void*)(gp), (AS3 void*)(lp), 16, 0, 0)

// ---------------- symmetric int8 row quantization (at BW floor) ----------------
template<int COLS>
__global__ __launch_bounds__(256)
void quant_rows_k(const float* __restrict__ src, int8_t* __restrict__ q,
                  float* __restrict__ scale)
{
    constexpr int PER = COLS / 256;   // 16
    static_assert(PER == 16, "pack assumes 16 elems/thread");
    const int row = blockIdx.x;
    const int t   = threadIdx.x;
    const float* s = src + (size_t)row * COLS + (size_t)t * PER;

    float v[PER];
    #pragma unroll
    for (int i = 0; i < PER; i += 4) {
        f32x4 x4 = *reinterpret_cast<const f32x4*>(s + i);
        v[i+0] = x4[0]; v[i+1] = x4[1]; v[i+2] = x4[2]; v[i+3] = x4[3];
    }
    float amax = 0.0f;
    #pragma unroll
    for (int i = 0; i < PER; ++i) amax = fmaxf(amax, fabsf(v[i]));

    #pragma unroll
    for (int off = 32; off > 0; off >>= 1)
        amax = fmaxf(amax, __shfl_xor(amax, off, 64));

    __shared__ float red[4];
    if ((t & 63) == 0) red[t >> 6] = amax;
    __syncthreads();
    amax = fmaxf(fmaxf(red[0], red[1]), fmaxf(red[2], red[3]));

    const float sc = fmaxf(amax, 1e-8f) / 127.0f;
    if (t == 0) scale[row] = sc;

    union { i32x4 v4; int8_t b[16]; } pk;
    #pragma unroll
    for (int i = 0; i < PER; ++i) {
        float r = rintf(v[i] / sc);
        r = fminf(127.0f, fmaxf(-127.0f, r));
        pk.b[i] = (int8_t)r;
    }
    *reinterpret_cast<i32x4*>(q + (size_t)row * COLS + (size_t)t * PER) = pk.v4;
}

// ---------------- int8 GEMM, 256x256 tile, 4-phase/K-tile, COUNTED vmcnt ----------------
// 512 threads = 8 waves (2M x 4N), wave tile 128x64, BK = 128 B (2 MFMA k-slices).
// Stage order (tile t+1, during tile t): P0:{b0,b1} P1:{b2,b3} P2:{a0,a2} P3:{a1,a3}
// Consumption (tile t+1): P0 needs b*,a0/a2; P2 needs a1/a3.
// Waits: end-P1 vmcnt(4), end-P3 vmcnt(2) -- never 0 in steady state.
#define BM 256
#define BN 256
#define BKB 128

__device__ __forceinline__ i32x4 mfma_i8(i32x4 a, i32x4 b, i32x4 c) {
    return __builtin_amdgcn_mfma_i32_16x16x64_i8(a, b, c, 0, 0, 0);
}

// WAIT: vmcnt immediate at END of this phase when staging; -1 = no wait (barrier only).
template<int P, int WAIT>
__device__ __forceinline__ void phase_fn(
    const int8_t* __restrict__ aB, const int8_t* __restrict__ bB,
    int kc0, int kc1,
    i32x4 (&acc)[8][4], i32x4 (&bf)[4][2],
    const int8_t* __restrict__ g0, int8_t* l0,
    const int8_t* __restrict__ g1, int8_t* l1,
    int t16, bool doStage)
{
    // ds-load this phase's A fragments (mi = 2P, 2P+1) x 2 k-slices
    i32x4 a00 = *reinterpret_cast<const i32x4*>(aB + (2*P)   * 2048 + kc0);
    i32x4 a01 = *reinterpret_cast<const i32x4*>(aB + (2*P)   * 2048 + kc1);
    i32x4 a10 = *reinterpret_cast<const i32x4*>(aB + (2*P+1) * 2048 + kc0);
    i32x4 a11 = *reinterpret_cast<const i32x4*>(aB + (2*P+1) * 2048 + kc1);
    if (P == 0) {   // B fragments for the whole K-tile, once
        #pragma unroll
        for (int ni = 0; ni < 4; ++ni) {
            bf[ni][0] = *reinterpret_cast<const i32x4*>(bB + ni * 2048 + kc0);
            bf[ni][1] = *reinterpret_cast<const i32x4*>(bB + ni * 2048 + kc1);
        }
    }
    if (doStage) {
        G2L16(g0, l0 + t16);
        G2L16(g1, l1 + t16);
    }
    asm volatile("" ::: "memory");
    __builtin_amdgcn_s_barrier();
    asm volatile("s_waitcnt lgkmcnt(0)" ::: "memory");
    __builtin_amdgcn_sched_barrier(0);
    __builtin_amdgcn_s_setprio(1);
    #pragma unroll
    for (int ni = 0; ni < 4; ++ni) {
        acc[2*P  ][ni] = mfma_i8(a00, bf[ni][0], acc[2*P  ][ni]);
        acc[2*P  ][ni] = mfma_i8(a01, bf[ni][1], acc[2*P  ][ni]);
        acc[2*P+1][ni] = mfma_i8(a10, bf[ni][0], acc[2*P+1][ni]);
        acc[2*P+1][ni] = mfma_i8(a11, bf[ni][1], acc[2*P+1][ni]);
    }
    __builtin_amdgcn_s_setprio(0);
    // counted wait AFTER compute, guarding next phase's ds_reads (cross-wave via barrier)
    if (WAIT >= 0) {
        if (doStage) {
            if (WAIT == 4) asm volatile("s_waitcnt vmcnt(4)" ::: "memory");
            else           asm volatile("s_waitcnt vmcnt(2)" ::: "memory");
        } else {
            asm volatile("s_waitcnt vmcnt(0)" ::: "memory");
        }
    }
    asm volatile("" ::: "memory");
    __builtin_amdgcn_s_barrier();
    asm volatile("" ::: "memory");
}

__global__ __launch_bounds__(512, 2)
void gemm_i8_k(const int8_t* __restrict__ A,    // [M][K]
               const int8_t* __restrict__ B,    // [N][K]
               const float*  __restrict__ sx,   // [M]
               const float*  __restrict__ sw,   // [N]
               const float*  __restrict__ bias, // [N]
               float* __restrict__ C,           // [M][N]
               int M, int N, int K)
{
    __shared__ int8_t lA[2][BM * BKB];   // 2 x 32 KiB
    __shared__ int8_t lB[2][BN * BKB];   // 2 x 32 KiB

    const int t    = threadIdx.x;
    const int lane = t & 63;
    const int wid  = t >> 6;
    const int wm   = wid >> 2;   // 0..1
    const int wn   = wid & 3;    // 0..3

    const int nwg = (int)gridDim.x;
    const int bid = (int)blockIdx.x;
    const int swz = ((nwg & 7) == 0) ? ((bid & 7) * (nwg >> 3) + (bid >> 3)) : bid;
    const int nbn = N / BN;
    const int bm  = swz / nbn;
    const int bn  = swz % nbn;

    // fragment-read addressing (XOR-swizzled, matches staged source swizzle)
    const int fr  = lane & 15;
    const int c4  = lane >> 4;
    const int sw8 = fr & 7;
    const int kc0 = ((c4    ) ^ sw8) * 16;
    const int kc1 = ((c4 + 4) ^ sw8) * 16;
    const int8_t* aB0 = &lA[0][(wm * 128 + fr) * BKB];
    const int8_t* aB1 = &lA[1][(wm * 128 + fr) * BKB];
    const int8_t* bB0 = &lB[0][(wn * 64  + fr) * BKB];
    const int8_t* bB1 = &lB[1][(wn * 64  + fr) * BKB];

    // staging: thread t covers row (t>>3) of each 64-row slab, chunk ((t&7)^(row&7))
    const int srow = t >> 3;                          // 0..63
    const int skc  = ((t & 7) ^ (srow & 7)) * 16;
    const int t16  = t * 16;
    const int8_t* pA = A + (size_t)(bm * BM + srow) * K + skc;
    const int8_t* pB = B + (size_t)(bn * BN + srow) * K + skc;
    const size_t r64  = (size_t)64  * K;
    const size_t r128 = (size_t)128 * K;

    // prologue: stage K-tile 0 into buffer 0 in steady-state issue order
    G2L16(pB,              &lB[0][0]     + t16);   // b0
    G2L16(pB + r64,        &lB[0][8192]  + t16);   // b1
    G2L16(pB + 2*r64,      &lB[0][16384] + t16);   // b2
    G2L16(pB + 3*r64,      &lB[0][24576] + t16);   // b3
    G2L16(pA,              &lA[0][0]     + t16);   // a0
    G2L16(pA + r128,       &lA[0][16384] + t16);   // a2
    G2L16(pA + r64,        &lA[0][8192]  + t16);   // a1
    G2L16(pA + r128 + r64, &lA[0][24576] + t16);   // a3
    asm volatile("s_waitcnt vmcnt(2)" ::: "memory");   // b*,a0,a2 resident; a1,a3 in flight
    __builtin_amdgcn_s_barrier();
    asm volatile("" ::: "memory");

    i32x4 acc[8][4] = {};
    i32x4 bf[4][2];

    const int NT = K / BKB;   // 32 (even)
    for (int tt = 0; tt < NT; tt += 2) {
        // ---- K-tile tt: read buf0, stage tile tt+1 -> buf1 ----
        {
            const size_t ko = (size_t)(tt + 1) * BKB;
            phase_fn<0,-1>(aB0, bB0, kc0, kc1, acc, bf, pB + ko,              &lB[1][0],     pB + ko + r64,        &lB[1][8192],  t16, true);
            phase_fn<1, 4>(aB0, bB0, kc0, kc1, acc, bf, pB + ko + 2*r64,      &lB[1][16384], pB + ko + 3*r64,      &lB[1][24576], t16, true);
            phase_fn<2,-1>(aB0, bB0, kc0, kc1, acc, bf, pA + ko,              &lA[1][0],     pA + ko + r128,       &lA[1][16384], t16, true);
            phase_fn<3, 2>(aB0, bB0, kc0, kc1, acc, bf, pA + ko + r64,        &lA[1][8192],  pA + ko + r128 + r64, &lA[1][24576], t16, true);
        }
        // ---- K-tile tt+1: read buf1, stage tile tt+2 -> buf0 ----
        {
            const bool st = (tt + 2) < NT;
            const size_t ko = st ? (size_t)(tt + 2) * BKB : 0;
            phase_fn<0,-1>(aB1, bB1, kc0, kc1, acc, bf, pB + ko,              &lB[0][0],     pB + ko + r64,        &lB[0][8192],  t16, st);
            phase_fn<1, 4>(aB1, bB1, kc0, kc1, acc, bf, pB + ko + 2*r64,      &lB[0][16384], pB + ko + 3*r64,      &lB[0][24576], t16, st);
            phase_fn<2,-1>(aB1, bB1, kc0, kc1, acc, bf, pA + ko,              &lA[0][0],     pA + ko + r128,       &lA[0][16384], t16, st);
            phase_fn<3, 2>(aB1, bB1, kc0, kc1, acc, bf, pA + ko + r64,        &lA[0][8192],  pA + ko + r128 + r64, &lA[0][24576], t16, st);
        }
    }

    // epilogue: dequant + bias
    const int r0 = bm * BM + wm * 128 + (c4 << 2);
    const int c0 = bn * BN + wn * 64 + fr;
    #pragma unroll
    for (int ni = 0; ni < 4; ++ni) {
        const int c = c0 + ni * 16;
        const float swc = sw[c];
        const float bc  = bias[c];
        #pragma unroll
        for (int mi = 0; mi < 8; ++mi) {
            const int rb = r0 + mi * 16;
            #pragma unroll
            for (int j = 0; j < 4; ++j) {
                const int r = rb + j;
                C[(size_t)r * N + c] = (float)acc[mi][ni][j] * sx[r] * swc + bc;
            }
        }
    }
}

extern "C" void kernel_launch(void* const* d_in, const int* in_sizes, int n_in,
                              void* d_out, int out_size, void* d_ws, size_t ws_size,
                              hipStream_t stream) {
    const float* x    = (const float*)d_in[0];
    const float* w    = (const float*)d_in[1];
    const float* bias = (const float*)d_in[2];
    float* out = (float*)d_out;

    const int dout   = in_sizes[2];          // 16384
    const int din    = in_sizes[1] / dout;   // 4096
    const int tokens = in_sizes[0] / din;    // 4096

    char* ws = (char*)d_ws;
    float*  sx = (float*)ws;
    float*  sw = (float*)(ws + 16384);
    int8_t* xq = (int8_t*)(ws + 16384 + 65536);
    int8_t* wq = xq + (size_t)tokens * din;

    quant_rows_k<4096><<<tokens, 256, 0, stream>>>(x, xq, sx);
    quant_rows_k<4096><<<dout,   256, 0, stream>>>(w, wq, sw);

    const int grid = (tokens / BM) * (dout / BN);
    gemm_i8_k<<<grid, 512, 0, stream>>>(xq, wq, sx, sw, bias, out, tokens, dout, din);
}

// Round 5
// 415.616 us; speedup vs baseline: 1.3133x; 1.0172x over previous
//
#include <hip/hip_runtime.h>
#include <stdint.h>

typedef int   i32x4 __attribute__((ext_vector_type(4)));
typedef float f32x4 __attribute__((ext_vector_type(4)));

#define AS1 __attribute__((address_space(1)))
#define AS3 __attribute__((address_space(3)))
#define G2L16(gp, lp) __builtin_amdgcn_global_load_lds((const AS1 void*)(gp), (AS3 void*)(lp), 16, 0, 0)

// ---------------- symmetric int8 row quantization (at BW floor) ----------------
template<int COLS>
__global__ __launch_bounds__(256)
void quant_rows_k(const float* __restrict__ src, int8_t* __restrict__ q,
                  float* __restrict__ scale)
{
    constexpr int PER = COLS / 256;   // 16
    static_assert(PER == 16, "pack assumes 16 elems/thread");
    const int row = blockIdx.x;
    const int t   = threadIdx.x;
    const float* s = src + (size_t)row * COLS + (size_t)t * PER;

    float v[PER];
    #pragma unroll
    for (int i = 0; i < PER; i += 4) {
        f32x4 x4 = *reinterpret_cast<const f32x4*>(s + i);
        v[i+0] = x4[0]; v[i+1] = x4[1]; v[i+2] = x4[2]; v[i+3] = x4[3];
    }
    float amax = 0.0f;
    #pragma unroll
    for (int i = 0; i < PER; ++i) amax = fmaxf(amax, fabsf(v[i]));

    #pragma unroll
    for (int off = 32; off > 0; off >>= 1)
        amax = fmaxf(amax, __shfl_xor(amax, off, 64));

    __shared__ float red[4];
    if ((t & 63) == 0) red[t >> 6] = amax;
    __syncthreads();
    amax = fmaxf(fmaxf(red[0], red[1]), fmaxf(red[2], red[3]));

    const float sc = fmaxf(amax, 1e-8f) / 127.0f;
    if (t == 0) scale[row] = sc;

    union { i32x4 v4; int8_t b[16]; } pk;
    #pragma unroll
    for (int i = 0; i < PER; ++i) {
        float r = rintf(v[i] / sc);
        r = fminf(127.0f, fmaxf(-127.0f, r));
        pk.b[i] = (int8_t)r;
    }
    *reinterpret_cast<i32x4*>(q + (size_t)row * COLS + (size_t)t * PER) = pk.v4;
}

// ---------------- int8 GEMM, 256x256 tile, cross-phase fragment prefetch ----------------
// 512 threads = 8 waves (2M x 4N), wave tile 128x64, BK = 128 B (2 k-slices of x64).
// Phases: P0=(ks0,mlo) P1=(ks0,mhi) P2=(ks1,mlo) P3=(ks1,mhi).
// Cross-wave-safe rule: every ds_read is preceded by {each wave's vmcnt draining the
// producing G2L} + a barrier. s4={a1,a3} drains at END of P0 (after MFMA) -> barrier;
// its first read (A1x) is in-phase at P1. P2/P3 operands are prefetched a phase early.
// Stage (tile t+1 during t): P0:{b0,b1} P1:{b2,b3} P2:{a0,a2} P3:{a1,a3}.
// Per-wave ledger (steady): entry s4_X(2); P0 +s1_Y; end-P0 vmcnt(2) [drain s4_X];
// P1 +s2_Y; P2 +s3_Y; P3 +s4_Y (8 outstanding); end-P3 vmcnt(2) [drain s1-s3_Y].
#define BM 256
#define BN 256
#define BKB 128

__device__ __forceinline__ i32x4 mfma_i8(i32x4 a, i32x4 b, i32x4 c) {
    return __builtin_amdgcn_mfma_i32_16x16x64_i8(a, b, c, 0, 0, 0);
}
__device__ __forceinline__ i32x4 ldsld(const int8_t* p) {
    return *reinterpret_cast<const i32x4*>(p);
}
#define FENCE asm volatile("" ::: "memory")
#define BAR   do { FENCE; __builtin_amdgcn_s_barrier(); FENCE; } while (0)

template<bool ST>
__device__ __forceinline__ void tile_fn(
    const int8_t* __restrict__ aB, const int8_t* __restrict__ bB,  // per-thread frag bases (cur buf)
    int kc0, int kc1, i32x4 (&acc)[8][4],
    const int8_t* __restrict__ gA, const int8_t* __restrict__ gB,  // per-thread stage src (next tile)
    int8_t* lAn, int8_t* lBn,                                      // next-buf LDS bases
    size_t r64, size_t r128, int t16)
{
    // ================= P0: MFMA (ks0, m 0-3) =================
    // in-phase reads; producers (s1,s2,s3 of this buf) drained at prev end-P3 + BAR
    i32x4 A00 = ldsld(aB + 0*2048 + kc0);
    i32x4 A01 = ldsld(aB + 1*2048 + kc0);
    i32x4 A02 = ldsld(aB + 2*2048 + kc0);
    i32x4 A03 = ldsld(aB + 3*2048 + kc0);
    i32x4 B00 = ldsld(bB + 0*2048 + kc0);
    i32x4 B01 = ldsld(bB + 1*2048 + kc0);
    i32x4 B02 = ldsld(bB + 2*2048 + kc0);
    i32x4 B03 = ldsld(bB + 3*2048 + kc0);
    if (ST) {                                   // stage s1 = {b0,b1}
        G2L16(gB,       lBn + t16);
        G2L16(gB + r64, lBn + 8192 + t16);
    }
    __builtin_amdgcn_s_setprio(1);
    acc[0][0] = mfma_i8(A00, B00, acc[0][0]);
    acc[1][0] = mfma_i8(A01, B00, acc[1][0]);
    acc[2][0] = mfma_i8(A02, B00, acc[2][0]);
    acc[3][0] = mfma_i8(A03, B00, acc[3][0]);
    acc[0][1] = mfma_i8(A00, B01, acc[0][1]);
    acc[1][1] = mfma_i8(A01, B01, acc[1][1]);
    acc[2][1] = mfma_i8(A02, B01, acc[2][1]);
    acc[3][1] = mfma_i8(A03, B01, acc[3][1]);
    acc[0][2] = mfma_i8(A00, B02, acc[0][2]);
    acc[1][2] = mfma_i8(A01, B02, acc[1][2]);
    acc[2][2] = mfma_i8(A02, B02, acc[2][2]);
    acc[3][2] = mfma_i8(A03, B02, acc[3][2]);
    acc[0][3] = mfma_i8(A00, B03, acc[0][3]);
    acc[1][3] = mfma_i8(A01, B03, acc[1][3]);
    acc[2][3] = mfma_i8(A02, B03, acc[2][3]);
    acc[3][3] = mfma_i8(A03, B03, acc[3][3]);
    __builtin_amdgcn_s_setprio(0);
    // drain prev tile's s4 = {a1,a3} of CURRENT buf (all waves, then barrier)
    if (ST) asm volatile("s_waitcnt vmcnt(2)" ::: "memory");
    else    asm volatile("s_waitcnt vmcnt(0)" ::: "memory");
    BAR;
    // ================= P1: MFMA (ks0, m 4-7) =================
    // in-phase reads: a1/a3 @ kc0 (safe: s4 drained by ALL waves + barrier above)
    i32x4 A10 = ldsld(aB + 4*2048 + kc0);
    i32x4 A11 = ldsld(aB + 5*2048 + kc0);
    i32x4 A12 = ldsld(aB + 6*2048 + kc0);
    i32x4 A13 = ldsld(aB + 7*2048 + kc0);
    // prefetch P2 frags (ks1 of a0/a2 and b_wn -- resident)
    i32x4 A20 = ldsld(aB + 0*2048 + kc1);
    i32x4 A21 = ldsld(aB + 1*2048 + kc1);
    i32x4 A22 = ldsld(aB + 2*2048 + kc1);
    i32x4 A23 = ldsld(aB + 3*2048 + kc1);
    i32x4 B10 = ldsld(bB + 0*2048 + kc1);
    i32x4 B11 = ldsld(bB + 1*2048 + kc1);
    i32x4 B12 = ldsld(bB + 2*2048 + kc1);
    i32x4 B13 = ldsld(bB + 3*2048 + kc1);
    if (ST) {                                   // stage s2 = {b2,b3}
        G2L16(gB + 2*r64, lBn + 16384 + t16);
        G2L16(gB + 3*r64, lBn + 24576 + t16);
    }
    __builtin_amdgcn_s_setprio(1);
    acc[4][0] = mfma_i8(A10, B00, acc[4][0]);
    acc[5][0] = mfma_i8(A11, B00, acc[5][0]);
    acc[6][0] = mfma_i8(A12, B00, acc[6][0]);
    acc[7][0] = mfma_i8(A13, B00, acc[7][0]);
    acc[4][1] = mfma_i8(A10, B01, acc[4][1]);
    acc[5][1] = mfma_i8(A11, B01, acc[5][1]);
    acc[6][1] = mfma_i8(A12, B01, acc[6][1]);
    acc[7][1] = mfma_i8(A13, B01, acc[7][1]);
    acc[4][2] = mfma_i8(A10, B02, acc[4][2]);
    acc[5][2] = mfma_i8(A11, B02, acc[5][2]);
    acc[6][2] = mfma_i8(A12, B02, acc[6][2]);
    acc[7][2] = mfma_i8(A13, B02, acc[7][2]);
    acc[4][3] = mfma_i8(A10, B03, acc[4][3]);
    acc[5][3] = mfma_i8(A11, B03, acc[5][3]);
    acc[6][3] = mfma_i8(A12, B03, acc[6][3]);
    acc[7][3] = mfma_i8(A13, B03, acc[7][3]);
    __builtin_amdgcn_s_setprio(0);
    BAR;
    // ================= P2: MFMA (ks1, m 0-3) =================
    // prefetch P3 frags (ks1 of a1/a3 -- drained at end-P0 + barriers)
    i32x4 A30 = ldsld(aB + 4*2048 + kc1);
    i32x4 A31 = ldsld(aB + 5*2048 + kc1);
    i32x4 A32 = ldsld(aB + 6*2048 + kc1);
    i32x4 A33 = ldsld(aB + 7*2048 + kc1);
    if (ST) {                                   // stage s3 = {a0,a2}
        G2L16(gA,        lAn + t16);
        G2L16(gA + r128, lAn + 16384 + t16);
    }
    __builtin_amdgcn_s_setprio(1);
    acc[0][0] = mfma_i8(A20, B10, acc[0][0]);
    acc[1][0] = mfma_i8(A21, B10, acc[1][0]);
    acc[2][0] = mfma_i8(A22, B10, acc[2][0]);
    acc[3][0] = mfma_i8(A23, B10, acc[3][0]);
    acc[0][1] = mfma_i8(A20, B11, acc[0][1]);
    acc[1][1] = mfma_i8(A21, B11, acc[1][1]);
    acc[2][1] = mfma_i8(A22, B11, acc[2][1]);
    acc[3][1] = mfma_i8(A23, B11, acc[3][1]);
    acc[0][2] = mfma_i8(A20, B12, acc[0][2]);
    acc[1][2] = mfma_i8(A21, B12, acc[1][2]);
    acc[2][2] = mfma_i8(A22, B12, acc[2][2]);
    acc[3][2] = mfma_i8(A23, B12, acc[3][2]);
    acc[0][3] = mfma_i8(A20, B13, acc[0][3]);
    acc[1][3] = mfma_i8(A21, B13, acc[1][3]);
    acc[2][3] = mfma_i8(A22, B13, acc[2][3]);
    acc[3][3] = mfma_i8(A23, B13, acc[3][3]);
    __builtin_amdgcn_s_setprio(0);
    BAR;
    // ================= P3: MFMA (ks1, m 4-7), no reads =================
    if (ST) {                                   // stage s4 = {a1,a3}
        G2L16(gA + r64,        lAn + 8192 + t16);
        G2L16(gA + r128 + r64, lAn + 24576 + t16);
    }
    __builtin_amdgcn_s_setprio(1);
    acc[4][0] = mfma_i8(A30, B10, acc[4][0]);
    acc[5][0] = mfma_i8(A31, B10, acc[5][0]);
    acc[6][0] = mfma_i8(A32, B10, acc[6][0]);
    acc[7][0] = mfma_i8(A33, B10, acc[7][0]);
    acc[4][1] = mfma_i8(A30, B11, acc[4][1]);
    acc[5][1] = mfma_i8(A31, B11, acc[5][1]);
    acc[6][1] = mfma_i8(A32, B11, acc[6][1]);
    acc[7][1] = mfma_i8(A33, B11, acc[7][1]);
    acc[4][2] = mfma_i8(A30, B12, acc[4][2]);
    acc[5][2] = mfma_i8(A31, B12, acc[5][2]);
    acc[6][2] = mfma_i8(A32, B12, acc[6][2]);
    acc[7][2] = mfma_i8(A33, B12, acc[7][2]);
    acc[4][3] = mfma_i8(A30, B13, acc[4][3]);
    acc[5][3] = mfma_i8(A31, B13, acc[5][3]);
    acc[6][3] = mfma_i8(A32, B13, acc[6][3]);
    acc[7][3] = mfma_i8(A33, B13, acc[7][3]);
    __builtin_amdgcn_s_setprio(0);
    if (ST) asm volatile("s_waitcnt vmcnt(2)" ::: "memory");  // drain s1-s3 of next tile; keep s4
    BAR;
}

__global__ __launch_bounds__(512, 2)
void gemm_i8_k(const int8_t* __restrict__ A,    // [M][K]
               const int8_t* __restrict__ B,    // [N][K]
               const float*  __restrict__ sx,   // [M]
               const float*  __restrict__ sw,   // [N]
               const float*  __restrict__ bias, // [N]
               float* __restrict__ C,           // [M][N]
               int M, int N, int K)
{
    __shared__ int8_t lA[2][BM * BKB];   // 2 x 32 KiB
    __shared__ int8_t lB[2][BN * BKB];   // 2 x 32 KiB

    const int t    = threadIdx.x;
    const int lane = t & 63;
    const int wid  = t >> 6;
    const int wm   = wid >> 2;   // 0..1
    const int wn   = wid & 3;    // 0..3

    const int nwg = (int)gridDim.x;
    const int bid = (int)blockIdx.x;
    const int swz = ((nwg & 7) == 0) ? ((bid & 7) * (nwg >> 3) + (bid >> 3)) : bid;
    const int nbn = N / BN;
    const int bm  = swz / nbn;
    const int bn  = swz % nbn;

    // fragment-read addressing (XOR-swizzled, matches staged source swizzle)
    const int fr  = lane & 15;
    const int c4  = lane >> 4;
    const int sw8 = fr & 7;
    const int kc0 = ((c4    ) ^ sw8) * 16;
    const int kc1 = ((c4 + 4) ^ sw8) * 16;
    const int8_t* aB0 = &lA[0][(wm * 128 + fr) * BKB];
    const int8_t* aB1 = &lA[1][(wm * 128 + fr) * BKB];
    const int8_t* bB0 = &lB[0][(wn * 64  + fr) * BKB];
    const int8_t* bB1 = &lB[1][(wn * 64  + fr) * BKB];

    // staging: thread t covers row (t>>3) of each 64-row slab, chunk ((t&7)^(row&7))
    const int srow = t >> 3;                          // 0..63
    const int skc  = ((t & 7) ^ (srow & 7)) * 16;
    const int t16  = t * 16;
    const int8_t* pA = A + (size_t)(bm * BM + srow) * K + skc;
    const int8_t* pB = B + (size_t)(bn * BN + srow) * K + skc;
    const size_t r64  = (size_t)64  * K;
    const size_t r128 = (size_t)128 * K;

    // prologue: stage K-tile 0 into buffer 0, order s1,s2,s3,s4
    G2L16(pB,              &lB[0][0]     + t16);   // b0
    G2L16(pB + r64,        &lB[0][8192]  + t16);   // b1
    G2L16(pB + 2*r64,      &lB[0][16384] + t16);   // b2
    G2L16(pB + 3*r64,      &lB[0][24576] + t16);   // b3
    G2L16(pA,              &lA[0][0]     + t16);   // a0
    G2L16(pA + r128,       &lA[0][16384] + t16);   // a2
    G2L16(pA + r64,        &lA[0][8192]  + t16);   // a1
    G2L16(pA + r128 + r64, &lA[0][24576] + t16);   // a3
    asm volatile("s_waitcnt vmcnt(2)" ::: "memory");   // b*,a0,a2 resident; a1,a3 in flight
    BAR;

    i32x4 acc[8][4] = {};

    const int NT = K / BKB;   // 32 (even)
    for (int tt = 0; tt + 2 < NT; tt += 2) {
        const size_t ko1 = (size_t)(tt + 1) * BKB;
        tile_fn<true>(aB0, bB0, kc0, kc1, acc, pA + ko1, pB + ko1, &lA[1][0], &lB[1][0], r64, r128, t16);
        const size_t ko2 = (size_t)(tt + 2) * BKB;
        tile_fn<true>(aB1, bB1, kc0, kc1, acc, pA + ko2, pB + ko2, &lA[0][0], &lB[0][0], r64, r128, t16);
    }
    {   // last two tiles: NT-2 (stages NT-1), then NT-1 (no stage)
        const size_t ko1 = (size_t)(NT - 1) * BKB;
        tile_fn<true >(aB0, bB0, kc0, kc1, acc, pA + ko1, pB + ko1, &lA[1][0], &lB[1][0], r64, r128, t16);
        tile_fn<false>(aB1, bB1, kc0, kc1, acc, pA, pB, &lA[0][0], &lB[0][0], r64, r128, t16);
    }

    // epilogue: dequant + bias
    const int r0 = bm * BM + wm * 128 + (c4 << 2);
    const int c0 = bn * BN + wn * 64 + fr;
    #pragma unroll
    for (int ni = 0; ni < 4; ++ni) {
        const int c = c0 + ni * 16;
        const float swc = sw[c];
        const float bc  = bias[c];
        #pragma unroll
        for (int mi = 0; mi < 8; ++mi) {
            const int rb = r0 + mi * 16;
            #pragma unroll
            for (int j = 0; j < 4; ++j) {
                const int r = rb + j;
                C[(size_t)r * N + c] = (float)acc[mi][ni][j] * sx[r] * swc + bc;
            }
        }
    }
}

extern "C" void kernel_launch(void* const* d_in, const int* in_sizes, int n_in,
                              void* d_out, int out_size, void* d_ws, size_t ws_size,
                              hipStream_t stream) {
    const float* x    = (const float*)d_in[0];
    const float* w    = (const float*)d_in[1];
    const float* bias = (const float*)d_in[2];
    float* out = (float*)d_out;

    const int dout   = in_sizes[2];          // 16384
    const int din    = in_sizes[1] / dout;   // 4096
    const int tokens = in_sizes[0] / din;    // 4096

    char* ws = (char*)d_ws;
    float*  sx = (float*)ws;
    float*  sw = (float*)(ws + 16384);
    int8_t* xq = (int8_t*)(ws + 16384 + 65536);
    int8_t* wq = xq + (size_t)tokens * din;

    quant_rows_k<4096><<<tokens, 256, 0, stream>>>(x, xq, sx);
    quant_rows_k<4096><<<dout,   256, 0, stream>>>(w, wq, sw);

    const int grid = (tokens / BM) * (dout / BN);
    gemm_i8_k<<<grid, 512, 0, stream>>>(xq, wq, sx, sw, bias, out, tokens, dout, din);
}